// Round 3
// baseline (80.263 us; speedup 1.0000x reference)
//
#include <hip/hip_runtime.h>
#include <math.h>

// ROI adaptive max-pool to 7x7 (torch adaptive_max_pool2d bin semantics).
// feature_map: [B=2, C=256, H=50, W=50] fp32
// rois:        [R=192, 5] int32 (batch, x1, y1, x2, y2), 1<=w,h, x2<=W, y2<=H
// out:         [R, C, 7, 7] fp32
//
// Round 7: attack the latency chain. R5's per-bin while loops serialized
// ~10 L2 round trips per wave (2 loads in flight, full drain per bin).
// Now ONE row-loop over the ROI with a 4-deep load pipeline (4 independent
// loads issued per iteration) and register/scalar bin bookkeeping:
//  - running max m; scalar ye_cur = end row of current bin
//  - uniform while emits finished bins to LDS; bin overlap (<=1 row) is
//    handled by re-initializing m from the just-loaded row v[k]
//  - tail rows past y2 need NO value mask: the last bin completes at row
//    y2-1, so later maxes are dead (i==7, never stored). Only the absolute
//    buffer-end clamp is kept (last plane's trailing lanes).
// Everything else (float2 lanes, 8ch/block, 14.8KB LDS, 32 waves/CU,
// grid 6144 = XCD-partitioned channel groups) unchanged from R5.

#define OUT_N 7
#define WPB 4                 // waves per block
#define CHW 2                 // channels per wave (float2 col-pair lanes)
#define CPB (WPB * CHW)       // 8 channels per block
#define LDSW 66               // 64 cols + 2 pad
#define UNR 4                 // rows loaded per pipeline batch

__global__ __launch_bounds__(256, 8) void roicrop_kernel(
    const float* __restrict__ fm,
    const int* __restrict__ rois,
    float* __restrict__ out,
    int R, int C, int H, int W, int nfm)
{
    __shared__ float tw[CPB][OUT_N][LDSW];   // 14.8 KB

    const int lane = threadIdx.x & 63;
    const int wave = threadIdx.x >> 6;        // 0..3
    const int cg_per_r = C / CPB;             // 32
    const int r  = blockIdx.x / cg_per_r;
    const int cg = blockIdx.x - r * cg_per_r; // XCD = cg % 8 under round-robin
                                              // dispatch -> 640KB fm footprint
                                              // per XCD L2 (resident)

    const int csub = lane >> 5;               // channel within wave: 0..1
    const int l2   = lane & 31;               // float2 lane within channel
    const int c    = cg * CPB + wave * CHW + csub;
    const int wc   = wave * CHW + csub;       // channel-in-block

    const int* roi = rois + r * 5;
    const int b  = roi[0];
    const int x1 = roi[1];
    const int y1 = roi[2];
    const int x2 = roi[3];
    const int y2 = roi[4];
    const int h = y2 - y1;
    const int w = x2 - x1;

    // Lane covers absolute columns [x0+2*l2, x0+2*l2+1]; x0, W even => a lane
    // is fully inside its row or fully past it (past-row values never read by
    // the epilogue). Only hazard: absolute buffer end -> one index clamp.
    const int x0 = x1 & ~1;
    const unsigned colb = (unsigned)(x0 + 2 * l2);
    const unsigned base = (unsigned)(b * C + c) * (unsigned)(H * W) + colb;
    const unsigned lim  = (unsigned)(nfm - 2);

    int bi = 0;                                    // current output bin
    int ye_cur = y1 + (h + OUT_N - 1) / OUT_N;     // end row of bin 0
    float2 m = make_float2(-INFINITY, -INFINITY);

    for (int y = y1; y < y2; y += UNR) {
        // 4 independent loads in flight (addresses independent of m/bi).
        float2 v[UNR];
        #pragma unroll
        for (int k = 0; k < UNR; ++k) {
            unsigned ia = base + (unsigned)((y + k) * W);
            if (ia > lim) ia = lim;                // buffer-end safety only
            v[k] = *reinterpret_cast<const float2*>(fm + ia);
        }
        // Bin bookkeeping: all branches are ROI-uniform (scalar).
        #pragma unroll
        for (int k = 0; k < UNR; ++k) {
            m.x = fmaxf(m.x, v[k].x);
            m.y = fmaxf(m.y, v[k].y);
            while (bi < OUT_N && y + k + 1 == ye_cur) {
                *reinterpret_cast<float2*>(&tw[wc][bi][2 * l2]) = m;
                ++bi;
                if (bi < OUT_N) {
                    const int ys_n = y1 + (bi * h) / OUT_N;   // new bin start
                    ye_cur = y1 + ((bi + 1) * h + OUT_N - 1) / OUT_N;
                    // bins overlap by <=1 row; the overlap row is y+k
                    m = (ys_n <= y + k) ? v[k]
                                        : make_float2(-INFINITY, -INFINITY);
                }
            }
        }
    }
    __syncthreads();

    // Epilogue: CPB*49 = 392 outputs, 256 threads -> 2 rounds. Column bins
    // reduce from LDS (x0-based indexing, shifted by off = x1-x0).
    const int off = x1 - x0;
    float* obase = out + ((size_t)r * C + cg * CPB) * (OUT_N * OUT_N);
    for (int o = threadIdx.x; o < CPB * OUT_N * OUT_N; o += 256) {
        const int twc = o / (OUT_N * OUT_N);
        const int l   = o - twc * (OUT_N * OUT_N);
        const int i   = l / OUT_N;
        const int j   = l - i * OUT_N;
        const int xs  = (j * w) / OUT_N;
        const int xe  = ((j + 1) * w + OUT_N - 1) / OUT_N;
        float m2 = -INFINITY;
        for (int dx = xs; dx < xe; ++dx) {
            m2 = fmaxf(m2, tw[twc][i][off + dx]);
        }
        obase[o] = m2;                         // fully coalesced: offset == o
    }
}

extern "C" void kernel_launch(void* const* d_in, const int* in_sizes, int n_in,
                              void* d_out, int out_size, void* d_ws, size_t ws_size,
                              hipStream_t stream)
{
    const float* fm = (const float*)d_in[0];
    const int* rois = (const int*)d_in[1];
    float* out      = (float*)d_out;

    const int R = in_sizes[1] / 5;                        // 192
    const int C = out_size / (R * OUT_N * OUT_N);         // 256
    const int H = 50;
    const int W = 50;
    const int nfm = in_sizes[0];                          // B*C*H*W elements

    const int grid = R * (C / CPB);                       // 6144
    roicrop_kernel<<<grid, 256, 0, stream>>>(fm, rois, out, R, C, H, W, nfm);
}